// Round 4
// baseline (172.152 us; speedup 1.0000x reference)
//
#include <hip/hip_runtime.h>
#include <hip/hip_fp16.h>
#include <math.h>

#define DFEAT 128
typedef unsigned long long u64;
typedef unsigned int u32;
#define ENDK 0xFFFFFFFFFFFFFFFFULL

// Fused kernel, split by block range:
//  - blocks [0, eluBlocks): emb2[i] = fp16( 2*elu(x[i]*w[i%D]) ), plus a zeros
//    row at index N (sentinel target).
//  - blocks [eluBlocks, ..): linked-list binning via atomicExch; nxt[e] is a
//    coalesced 8B stream store. nxt[E] self-terminates (sentinel slot).
__global__ void fused_elu_bin_kernel(const float* __restrict__ x,
                                     const float* __restrict__ w,
                                     __half* __restrict__ emb2,
                                     int total4, int total4ext,
                                     const int* __restrict__ src,
                                     const int* __restrict__ dst, int E,
                                     u64* __restrict__ head,
                                     u64* __restrict__ nxt,
                                     int eluBlocks) {
    if ((int)blockIdx.x < eluBlocks) {
        int idx = blockIdx.x * blockDim.x + threadIdx.x;   // group of 4 elements
        if (idx >= total4ext) return;
        uint2 pk = make_uint2(0u, 0u);                      // zeros row for idx>=total4
        if (idx < total4) {
            float4 xv = ((const float4*)x)[idx];
            float4 wv = ((const float4*)w)[idx & (DFEAT / 4 - 1)];
            float a, r0, r1, r2, r3;
            a = xv.x * wv.x; r0 = 2.0f * (a > 0.0f ? a : (__expf(a) - 1.0f));
            a = xv.y * wv.y; r1 = 2.0f * (a > 0.0f ? a : (__expf(a) - 1.0f));
            a = xv.z * wv.z; r2 = 2.0f * (a > 0.0f ? a : (__expf(a) - 1.0f));
            a = xv.w * wv.w; r3 = 2.0f * (a > 0.0f ? a : (__expf(a) - 1.0f));
            __half2 h01 = __floats2half2_rn(r0, r1);
            __half2 h23 = __floats2half2_rn(r2, r3);
            pk.x = *(u32*)&h01;
            pk.y = *(u32*)&h23;
        }
        ((uint2*)emb2)[idx] = pk;
    } else {
        int e = (blockIdx.x - eluBlocks) * blockDim.x + threadIdx.x;
        if (e >= E) return;
        if (e == 0) nxt[E] = ENDK;                 // sentinel slot self-terminates
        int s = src[e];
        int d = dst[e];
        u64 packed = ((u64)(u32)s << 32) | (u32)e;
        nxt[e] = atomicExch(&head[d], packed);     // coalesced 8B store of old head
    }
}

// One wave per 2 destination nodes; lane owns 2 fp16 columns (one u32).
// Branch-free body: sentinel chains read the zeros row (accumulate 0) and the
// self-looping nxt[E]; min() clamps make sentinel addresses safe.
__global__ void gather_ll_kernel(const u32* __restrict__ embu,   // (N+1)*64 u32
                                 const u64* __restrict__ head,
                                 const u64* __restrict__ nxt,
                                 float* __restrict__ out, int N, int E) {
    int wid = (blockIdx.x * blockDim.x + threadIdx.x) >> 6;
    int lane = threadIdx.x & 63;
    int nA = wid * 2;
    int nB = nA + 1;
    if (nA >= N) return;
    u64 curA = head[nA];
    u64 curB = (nB < N) ? head[nB] : ENDK;
    float2 accA = make_float2(0.0f, 0.0f);
    float2 accB = make_float2(0.0f, 0.0f);
    const u32 uN = (u32)N, uE = (u32)E;
    while (curA != ENDK || curB != ENDK) {
        u32 rA = min((u32)(curA >> 32), uN);       // sentinel -> zeros row N
        u32 eA = min((u32)curA, uE);               // sentinel -> self-loop slot E
        u32 rB = min((u32)(curB >> 32), uN);
        u32 eB = min((u32)curB, uE);
        u32 hA = embu[rA * 64u + (u32)lane];
        u32 hB = embu[rB * 64u + (u32)lane];
        curA = nxt[eA];
        curB = nxt[eB];
        float2 fA = __half22float2(*(__half2*)&hA);
        float2 fB = __half22float2(*(__half2*)&hB);
        accA.x += fA.x; accA.y += fA.y;
        accB.x += fB.x; accB.y += fB.y;
    }
    ((float2*)out)[(u32)nA * 64u + (u32)lane] = accA;
    if (nB < N) ((float2*)out)[(u32)nB * 64u + (u32)lane] = accB;
}

// Fallback if ws too small: fuse elu into gather, fp32 atomic scatter.
__global__ void scatter_fused_kernel(const float* __restrict__ x,
                                     const float* __restrict__ w,
                                     const int* __restrict__ src,
                                     const int* __restrict__ dst,
                                     float* __restrict__ out, int E) {
    int t = blockIdx.x * blockDim.x + threadIdx.x;
    int edge = t >> 5;
    int lane = t & 31;
    if (edge >= E) return;
    int s = src[edge];
    int d = dst[edge];
    float4 xv = ((const float4*)(x + (size_t)s * DFEAT))[lane];
    float4 wv = ((const float4*)w)[lane];
    float4 v;
    float a;
    a = xv.x * wv.x; v.x = 2.0f * (a > 0.0f ? a : (__expf(a) - 1.0f));
    a = xv.y * wv.y; v.y = 2.0f * (a > 0.0f ? a : (__expf(a) - 1.0f));
    a = xv.z * wv.z; v.z = 2.0f * (a > 0.0f ? a : (__expf(a) - 1.0f));
    a = xv.w * wv.w; v.w = 2.0f * (a > 0.0f ? a : (__expf(a) - 1.0f));
    float* op = out + (size_t)d * DFEAT + lane * 4;
    unsafeAtomicAdd(op + 0, v.x);
    unsafeAtomicAdd(op + 1, v.y);
    unsafeAtomicAdd(op + 2, v.z);
    unsafeAtomicAdd(op + 3, v.w);
}

extern "C" void kernel_launch(void* const* d_in, const int* in_sizes, int n_in,
                              void* d_out, int out_size, void* d_ws, size_t ws_size,
                              hipStream_t stream) {
    const float* x   = (const float*)d_in[0];   // graph_embedding [N, 128]
    const float* w   = (const float*)d_in[1];   // weight [1, 128]
    const int*   src = (const int*)d_in[3];     // src [E]
    const int*   dst = (const int*)d_in[4];     // dst [E]
    float* out = (float*)d_out;

    const int ND = in_sizes[0];          // N * 128
    const int N  = ND / DFEAT;           // 50000
    const int E  = in_sizes[2];          // 800000

    size_t emb_bytes  = (((size_t)(N + 1) * DFEAT) * sizeof(__half) + 15) & ~(size_t)15;
    size_t head_bytes = ((size_t)N * sizeof(u64) + 15) & ~(size_t)15;
    size_t nxt_bytes  = (size_t)(E + 1) * sizeof(u64);
    size_t total = emb_bytes + head_bytes + nxt_bytes;

    if (ws_size >= total) {
        char* p = (char*)d_ws;
        __half* emb2 = (__half*)p;  p += emb_bytes;
        u64*    head = (u64*)p;     p += head_bytes;
        u64*    nxt  = (u64*)p;

        // sentinel-fill heads (0xFF bytes == ENDK)
        hipMemsetAsync(head, 0xFF, (size_t)N * sizeof(u64), stream);

        int total4    = ND / 4;                    // real rows
        int total4ext = total4 + DFEAT / 4;        // + zeros row N
        int eluBlocks = (total4ext + 255) / 256;
        int binBlocks = (E + 255) / 256;
        fused_elu_bin_kernel<<<eluBlocks + binBlocks, 256, 0, stream>>>(
            x, w, emb2, total4, total4ext, src, dst, E, head, nxt, eluBlocks);

        long long waves = (N + 1) / 2;
        long long thr = waves * 64;
        gather_ll_kernel<<<(int)((thr + 255) / 256), 256, 0, stream>>>(
            (const u32*)emb2, head, nxt, out, N, E);
    } else {
        hipMemsetAsync(d_out, 0, (size_t)out_size * sizeof(float), stream);
        long long threads = (long long)E * 32;
        scatter_fused_kernel<<<(int)((threads + 255) / 256), 256, 0, stream>>>(x, w, src, dst, out, E);
    }
}